// Round 1
// baseline (419.337 us; speedup 1.0000x reference)
//
#include <hip/hip_runtime.h>

#define NROW 8192
#define DIN  512
#define DOUT 256
#define NCHUNK 256
#define CLEN 32   // NCHUNK*CLEN == NROW

// ---------------- workspace layout (bytes) ----------------
constexpr size_t OFF_H      = 0;                              // 8192*256*4
constexpr size_t OFF_S1     = OFF_H + (size_t)NROW*DOUT*4;    // ---- memset region start
constexpr size_t OFF_S2     = OFF_S1 + NROW*4;
constexpr size_t OFF_RANK   = OFF_S2 + NROW*4;
constexpr size_t OFF_MISC   = OFF_RANK + NROW*4;              // [0]=enc-max u32, [1]=M1 float
constexpr size_t MEMSET_LEN = OFF_MISC + 256 - OFF_S1;        // s1,s2,rank,misc contiguous
constexpr size_t OFF_S1S    = OFF_MISC + 256;
constexpr size_t OFF_PERM   = OFF_S1S + NROW*4;
constexpr size_t OFF_WHI    = OFF_PERM + NROW*4;
constexpr size_t OFF_WLO    = OFF_WHI + NROW*4;
constexpr size_t OFF_PRELOS = OFF_WLO + NROW*4;               // 8193 floats, padded
constexpr size_t OFF_SUFHIS = OFF_PRELOS + 33024;
constexpr size_t OFF_CSLO   = OFF_SUFHIS + 33024;             // [NCHUNK] scalar chunk sums
constexpr size_t OFF_CSHI   = OFF_CSLO + 1024;
constexpr size_t OFF_TLO    = OFF_CSHI + 1024;                // [NCHUNK][256]
constexpr size_t OFF_THI    = OFF_TLO + (size_t)NCHUNK*DOUT*4;
constexpr size_t OFF_PRELO  = OFF_THI + (size_t)NCHUNK*DOUT*4;  // [8193][256]
constexpr size_t OFF_SUFHI  = OFF_PRELO + (size_t)(NROW+1)*DOUT*4;
constexpr size_t WS_NEED    = OFF_SUFHI + (size_t)(NROW+1)*DOUT*4;

typedef float f32x4 __attribute__((ext_vector_type(4)));
typedef short s16x8 __attribute__((ext_vector_type(8)));

// ---- fp32 -> bf16 split helpers (RNE) ----
__device__ __forceinline__ unsigned short bf16_rne(float f) {
  unsigned int u = __float_as_uint(f);
  return (unsigned short)((u + 0x7fffu + ((u >> 16) & 1u)) >> 16);
}
__device__ __forceinline__ unsigned short bf16_part(float f, bool lo) {
  unsigned short hi = bf16_rne(f);
  if (!lo) return hi;
  float r = f - __uint_as_float(((unsigned int)hi) << 16);
  return bf16_rne(r);
}
__device__ __forceinline__ s16x8 cvt8(const float4 u, const float4 v, bool lo) {
  s16x8 r;
  r[0] = (short)bf16_part(u.x, lo); r[1] = (short)bf16_part(u.y, lo);
  r[2] = (short)bf16_part(u.z, lo); r[3] = (short)bf16_part(u.w, lo);
  r[4] = (short)bf16_part(v.x, lo); r[5] = (short)bf16_part(v.y, lo);
  r[6] = (short)bf16_part(v.z, lo); r[7] = (short)bf16_part(v.w, lo);
  return r;
}

// ------- kernel 1: h = x @ W^T via split-bf16 MFMA --------------------------
// h = (xh+xl)(wh+wl)^T ~= xh*wh + xl*wh + xh*wl  (lo*lo term ~2^-18, dropped;
// split floor ~2^-17 rel -> |dh| ~ 1e-5, far below current absmax 9.8e-4).
// Tile 64x64, 512 blocks (2/CU), 4 waves in 2x2, each wave 32x32 = 2x2 frags
// of v_mfma_f32_16x16x32_bf16. LDS staged row-major [row][k] padded to 40
// bf16 (80 B pitch = 5*16 -> b128-aligned, frag reads verified conflict-free).
__global__ __launch_bounds__(256) void gemm_h_mfma(const float* __restrict__ x,
                                                   const float* __restrict__ W,
                                                   float* __restrict__ h) {
  __shared__ unsigned short As[64][40];  // 64 rows x 32 k (+8 pad)
  __shared__ unsigned short Bs[64][40];
  const int tid = threadIdx.x;
  const int rowBase = blockIdx.x * 64;
  const int colBase = blockIdx.y * 64;
  const int wid = tid >> 6, lane = tid & 63;
  const int wRow = wid >> 1, wCol = wid & 1;      // 2x2 wave grid
  const int lhi = lane >> 4, llo = lane & 15;

  f32x4 acc[2][2];
#pragma unroll
  for (int m = 0; m < 2; ++m)
#pragma unroll
    for (int n = 0; n < 2; ++n) acc[m][n] = (f32x4)(0.f);

  const int sr = tid >> 2;   // staging row 0..63
  const int sq = tid & 3;    // k-quarter (8 floats each)
  const float* xsrc = x + (size_t)(rowBase + sr) * DIN + sq * 8;
  const float* wsrc = W + (size_t)(colBase + sr) * DIN + sq * 8;

  for (int pass = 0; pass < 3; ++pass) {
    const bool aLo = (pass == 1);
    const bool bLo = (pass == 2);
    for (int k0 = 0; k0 < DIN; k0 += 32) {
      float4 a0 = *(const float4*)(xsrc + k0);
      float4 a1v = *(const float4*)(xsrc + k0 + 4);
      float4 b0 = *(const float4*)(wsrc + k0);
      float4 b1 = *(const float4*)(wsrc + k0 + 4);
      s16x8 av = cvt8(a0, a1v, aLo);
      s16x8 bv = cvt8(b0, b1, bLo);
      __syncthreads();  // previous step's frag reads complete
      *(s16x8*)&As[sr][sq * 8] = av;
      *(s16x8*)&Bs[sr][sq * 8] = bv;
      __syncthreads();  // staged tile visible
      s16x8 af[2], bf[2];
#pragma unroll
      for (int m = 0; m < 2; ++m)
        af[m] = *(const s16x8*)&As[wRow * 32 + m * 16 + llo][lhi * 8];
#pragma unroll
      for (int n = 0; n < 2; ++n)
        bf[n] = *(const s16x8*)&Bs[wCol * 32 + n * 16 + llo][lhi * 8];
#pragma unroll
      for (int m = 0; m < 2; ++m)
#pragma unroll
        for (int n = 0; n < 2; ++n)
          acc[m][n] = __builtin_amdgcn_mfma_f32_16x16x32_bf16(af[m], bf[n], acc[m][n], 0, 0, 0);
    }
  }
  // C/D layout (m89-verified): col = lane&15, row = (lane>>4)*4 + reg
#pragma unroll
  for (int m = 0; m < 2; ++m)
#pragma unroll
    for (int n = 0; n < 2; ++n) {
      const int col = colBase + wCol * 32 + n * 16 + llo;
#pragma unroll
      for (int j = 0; j < 4; ++j) {
        const int row = rowBase + wRow * 32 + m * 16 + lhi * 4 + j;
        h[(size_t)row * DOUT + col] = acc[m][n][j];
      }
    }
}

// ------- kernel 1b: s1 = h@a1, s2 = h@a2 (one wave per row) ----------------
__global__ __launch_bounds__(256) void s1s2_rows(const float* __restrict__ h,
                                                 const float* __restrict__ a1,
                                                 const float* __restrict__ a2,
                                                 float* __restrict__ s1,
                                                 float* __restrict__ s2) {
  const int wid = threadIdx.x >> 6, lane = threadIdx.x & 63;
  const int row = blockIdx.x * 4 + wid;
  float4 hv = *(const float4*)(h + (size_t)row * DOUT + (lane << 2));
  float4 A1 = *(const float4*)(a1 + (lane << 2));
  float4 A2 = *(const float4*)(a2 + (lane << 2));
  float p1 = hv.x * A1.x + hv.y * A1.y + hv.z * A1.z + hv.w * A1.w;
  float p2 = hv.x * A2.x + hv.y * A2.y + hv.z * A2.z + hv.w * A2.w;
#pragma unroll
  for (int off = 32; off > 0; off >>= 1) {
    p1 += __shfl_xor(p1, off);
    p2 += __shfl_xor(p2, off);
  }
  if (lane == 0) { s1[row] = p1; s2[row] = p2; }
}

// ------- kernel 2: rank by counting (atomicAdd into rank) + global max -----
__global__ __launch_bounds__(256) void rank_count(const float* __restrict__ s1,
                                                  int* __restrict__ rank,
                                                  unsigned int* __restrict__ miscu) {
  __shared__ float sj[1024];
  __shared__ float wm[4];
  const int t = threadIdx.x;
  const int ib = blockIdx.x, jc = blockIdx.y;
  const int j0 = jc * 1024;
  *(float4*)&sj[t << 2] = *(const float4*)(s1 + j0 + (t << 2));
  const int i = ib * 256 + t;
  const float v = s1[i];
  __syncthreads();
  int cnt = 0;
#pragma unroll 4
  for (int q = 0; q < 256; ++q) {
    float4 sv = *(const float4*)&sj[q << 2];
    int jg = j0 + (q << 2);
    cnt += (int)(sv.x < v) + (int)((sv.x == v) & (jg + 0 < i));
    cnt += (int)(sv.y < v) + (int)((sv.y == v) & (jg + 1 < i));
    cnt += (int)(sv.z < v) + (int)((sv.z == v) & (jg + 2 < i));
    cnt += (int)(sv.w < v) + (int)((sv.w == v) & (jg + 3 < i));
  }
  atomicAdd(&rank[i], cnt);
  if (jc == 0) {  // one layer computes global max of s1 (monotone-uint atomicMax)
    float m = v;
#pragma unroll
    for (int off = 32; off > 0; off >>= 1) m = fmaxf(m, __shfl_down(m, off));
    if ((t & 63) == 0) wm[t >> 6] = m;
    __syncthreads();
    if (t == 0) {
      float mm = fmaxf(fmaxf(wm[0], wm[1]), fmaxf(wm[2], wm[3]));
      unsigned int b = __float_as_uint(mm);
      unsigned int enc = (b & 0x80000000u) ? ~b : (b | 0x80000000u);
      atomicMax(miscu, enc);
    }
  }
}

// ------- kernel 3: scatter into sorted order + exp weights -----------------
__global__ __launch_bounds__(256) void scatter_w(const float* __restrict__ s1,
                                                 const int* __restrict__ rank,
                                                 const unsigned int* __restrict__ miscu,
                                                 float* __restrict__ miscf,
                                                 float* __restrict__ s1s,
                                                 int* __restrict__ perm,
                                                 float* __restrict__ w_hi,
                                                 float* __restrict__ w_lo) {
  const int i = blockIdx.x * 256 + threadIdx.x;
  unsigned int e = miscu[0];
  unsigned int b = (e & 0x80000000u) ? (e & 0x7fffffffu) : ~e;
  const float M1 = __uint_as_float(b);
  const float v = s1[i];
  const int r = rank[i];
  s1s[r] = v;
  perm[r] = i;
  w_hi[r] = __expf(v - M1);
  w_lo[r] = __expf(0.2f * (v - M1));
  if (i == 0) miscf[0] = M1;
}

// ------- kernel 4: per-chunk weighted totals + scalar chunk sums -----------
__global__ __launch_bounds__(256) void chunk_totals(const float* __restrict__ h,
                                                    const int* __restrict__ perm,
                                                    const float* __restrict__ w_hi,
                                                    const float* __restrict__ w_lo,
                                                    float* __restrict__ T_lo,
                                                    float* __restrict__ T_hi,
                                                    float* __restrict__ cs_lo,
                                                    float* __restrict__ cs_hi) {
  const int d = threadIdx.x, b = blockIdx.x;
  const int j0 = b * CLEN;
  float tlo = 0.f, thi = 0.f;
#pragma unroll
  for (int e = 0; e < CLEN; e += 4) {
    int4 p4 = *(const int4*)(perm + j0 + e);
    float4 wl4 = *(const float4*)(w_lo + j0 + e);
    float4 wh4 = *(const float4*)(w_hi + j0 + e);
    float h0 = h[(size_t)p4.x * DOUT + d];
    float h1 = h[(size_t)p4.y * DOUT + d];
    float h2 = h[(size_t)p4.z * DOUT + d];
    float h3 = h[(size_t)p4.w * DOUT + d];
    tlo += wl4.x * h0 + wl4.y * h1 + wl4.z * h2 + wl4.w * h3;
    thi += wh4.x * h0 + wh4.y * h1 + wh4.z * h2 + wh4.w * h3;
  }
  T_lo[b * DOUT + d] = tlo;
  T_hi[b * DOUT + d] = thi;
  if (d < 64) {  // wave 0: scalar sums of this chunk's weights
    float wl = (d < 32) ? w_lo[j0 + d] : 0.f;
    float wh = (d < 32) ? w_hi[j0 + d] : 0.f;
#pragma unroll
    for (int off = 32; off > 0; off >>= 1) {
      wl += __shfl_down(wl, off);
      wh += __shfl_down(wh, off);
    }
    if (d == 0) { cs_lo[b] = wl; cs_hi[b] = wh; }
  }
}

// ------- kernel 5: chunk-offset sums + materialize PreLo/SufHi + scalars ---
__global__ __launch_bounds__(256) void write_prefix(const float* __restrict__ h,
                                                    const int* __restrict__ perm,
                                                    const float* __restrict__ w_hi,
                                                    const float* __restrict__ w_lo,
                                                    const float* __restrict__ T_lo,
                                                    const float* __restrict__ T_hi,
                                                    const float* __restrict__ cs_lo,
                                                    const float* __restrict__ cs_hi,
                                                    float* __restrict__ PreLo,
                                                    float* __restrict__ SufHi,
                                                    float* __restrict__ prelo_s,
                                                    float* __restrict__ sufhi_s) {
  const int d = threadIdx.x, b = blockIdx.x;
  const int j0 = b * CLEN;
  // wave 0 additionally computes the scalar denominator prefixes
  if (d < 64) {
    float accp = 0.f, acct = 0.f;
    for (int p = d; p < NCHUNK; p += 64) {
      float cl = cs_lo[p], ch = cs_hi[p];
      accp += (p < b) ? cl : 0.f;
      acct += (p > b) ? ch : 0.f;
    }
#pragma unroll
    for (int off = 32; off > 0; off >>= 1) {
      accp += __shfl_down(accp, off);
      acct += __shfl_down(acct, off);
    }
    float pres  = __shfl(accp, 0);
    float tails = __shfl(acct, 0);
    float wl = (d < 32) ? w_lo[j0 + d] : 0.f;
    float wh = (d < 32) ? w_hi[j0 + d] : 0.f;
    float pl = wl, ph = wh;  // inclusive prefix over 32 lanes
#pragma unroll
    for (int off = 1; off < 32; off <<= 1) {
      float a = __shfl_up(pl, off);
      float c = __shfl_up(ph, off);
      if (d >= off) { pl += a; ph += c; }
    }
    float chunk_hi_tot = __shfl(ph, 31);
    if (d < 32) {
      prelo_s[j0 + d] = pres + (pl - wl);
      sufhi_s[j0 + d] = tails + (chunk_hi_tot - (ph - wh));
    }
    if (b == NCHUNK - 1 && d == 31) {
      prelo_s[NROW] = pres + pl;
      sufhi_s[NROW] = 0.f;
    }
  }
  float rl = 0.f, tail = 0.f;
#pragma unroll 8
  for (int p = 0; p < NCHUNK; ++p) {
    float vl = T_lo[p * DOUT + d];
    float vh = T_hi[p * DOUT + d];
    rl   += (p < b) ? vl : 0.f;
    tail += (p > b) ? vh : 0.f;
  }
  float hv[CLEN], wlv[CLEN], whv[CLEN];
  float ownHi = 0.f;
#pragma unroll
  for (int e = 0; e < CLEN; e += 4) {
    int4 p4 = *(const int4*)(perm + j0 + e);
    float4 wl4 = *(const float4*)(w_lo + j0 + e);
    float4 wh4 = *(const float4*)(w_hi + j0 + e);
    hv[e + 0] = h[(size_t)p4.x * DOUT + d];
    hv[e + 1] = h[(size_t)p4.y * DOUT + d];
    hv[e + 2] = h[(size_t)p4.z * DOUT + d];
    hv[e + 3] = h[(size_t)p4.w * DOUT + d];
    wlv[e + 0] = wl4.x; wlv[e + 1] = wl4.y; wlv[e + 2] = wl4.z; wlv[e + 3] = wl4.w;
    whv[e + 0] = wh4.x; whv[e + 1] = wh4.y; whv[e + 2] = wh4.z; whv[e + 3] = wh4.w;
    ownHi += wh4.x * hv[e] + wh4.y * hv[e + 1] + wh4.z * hv[e + 2] + wh4.w * hv[e + 3];
  }
  float shb = tail + ownHi;
  float preh = 0.f;
#pragma unroll
  for (int e = 0; e < CLEN; ++e) {
    size_t j = (size_t)(j0 + e);
    PreLo[j * DOUT + d] = rl;
    SufHi[j * DOUT + d] = shb - preh;
    rl   += wlv[e] * hv[e];
    preh += whv[e] * hv[e];
  }
  if (b == NCHUNK - 1) {
    PreLo[(size_t)NROW * DOUT + d] = rl;
    SufHi[(size_t)NROW * DOUT + d] = 0.f;
  }
}

// ---------------- kernel 6: per-row combine -------------------------------
__global__ __launch_bounds__(256) void finalize(const float* __restrict__ s2,
                                                const float* __restrict__ s1s,
                                                const float* __restrict__ miscf,
                                                const float* __restrict__ PreLo,
                                                const float* __restrict__ SufHi,
                                                const float* __restrict__ prelo_s,
                                                const float* __restrict__ sufhi_s,
                                                float* __restrict__ out) {
  const int wave = threadIdx.x >> 6, lane = threadIdx.x & 63;
  const int i = blockIdx.x * 4 + wave;
  const float c = s2[i];
  const float M1 = miscf[0];
  const float tval = -c;
  int lo = 0, hi = NROW;
  while (lo < hi) {
    int mid = (lo + hi) >> 1;
    if (s1s[mid] <= tval) lo = mid + 1; else hi = mid;
  }
  const int k = lo;
  const float u = c + M1;
  const float m = fmaxf(u, 0.2f * u);
  const float fh = __expf(u - m);
  const float fl = __expf(0.2f * u - m);
  const float den = fh * sufhi_s[k] + fl * prelo_s[k];
  const float inv = 1.f / den;
  float4 A = *(const float4*)(SufHi + (size_t)k * DOUT + (lane << 2));
  float4 B = *(const float4*)(PreLo + (size_t)k * DOUT + (lane << 2));
  float4 o;
  o.x = (fh * A.x + fl * B.x) * inv;
  o.y = (fh * A.y + fl * B.y) * inv;
  o.z = (fh * A.z + fl * B.z) * inv;
  o.w = (fh * A.w + fl * B.w) * inv;
  *(float4*)(out + (size_t)i * DOUT + (lane << 2)) = o;
}

extern "C" void kernel_launch(void* const* d_in, const int* in_sizes, int n_in,
                              void* d_out, int out_size, void* d_ws, size_t ws_size,
                              hipStream_t stream) {
  const float* x  = (const float*)d_in[0];
  const float* W  = (const float*)d_in[2];
  const float* a1 = (const float*)d_in[3];
  const float* a2 = (const float*)d_in[4];
  float* out = (float*)d_out;

  char* ws = (char*)d_ws;
  if (ws_size < WS_NEED) ws = (char*)d_in[1];  // fall back to unused adj buffer

  float*        h       = (float*)(ws + OFF_H);
  float*        s1      = (float*)(ws + OFF_S1);
  float*        s2      = (float*)(ws + OFF_S2);
  int*          rank    = (int*)  (ws + OFF_RANK);
  unsigned int* miscu   = (unsigned int*)(ws + OFF_MISC);
  float*        miscf   = (float*)(ws + OFF_MISC) + 1;
  float*        s1s     = (float*)(ws + OFF_S1S);
  int*          perm    = (int*)  (ws + OFF_PERM);
  float*        w_hi    = (float*)(ws + OFF_WHI);
  float*        w_lo    = (float*)(ws + OFF_WLO);
  float*        prelo_s = (float*)(ws + OFF_PRELOS);
  float*        sufhi_s = (float*)(ws + OFF_SUFHIS);
  float*        cs_lo   = (float*)(ws + OFF_CSLO);
  float*        cs_hi   = (float*)(ws + OFF_CSHI);
  float*        T_lo    = (float*)(ws + OFF_TLO);
  float*        T_hi    = (float*)(ws + OFF_THI);
  float*        PreLo   = (float*)(ws + OFF_PRELO);
  float*        SufHi   = (float*)(ws + OFF_SUFHI);

  // zero s1,s2,rank,misc (contiguous) for the atomic accumulations
  hipMemsetAsync(s1, 0, MEMSET_LEN, stream);

  gemm_h_mfma<<<dim3(NROW / 64, DOUT / 64), 256, 0, stream>>>(x, W, h);
  s1s2_rows<<<NROW / 4, 256, 0, stream>>>(h, a1, a2, s1, s2);
  rank_count<<<dim3(NROW / 256, 8), 256, 0, stream>>>(s1, rank, miscu);
  scatter_w<<<NROW / 256, 256, 0, stream>>>(s1, rank, miscu, miscf, s1s, perm, w_hi, w_lo);
  chunk_totals<<<NCHUNK, 256, 0, stream>>>(h, perm, w_hi, w_lo, T_lo, T_hi, cs_lo, cs_hi);
  write_prefix<<<NCHUNK, 256, 0, stream>>>(h, perm, w_hi, w_lo, T_lo, T_hi, cs_lo, cs_hi,
                                           PreLo, SufHi, prelo_s, sufhi_s);
  finalize<<<NROW / 4, 256, 0, stream>>>(s2, s1s, miscf, PreLo, SufHi, prelo_s, sufhi_s, out);
}

// Round 2
// 380.964 us; speedup vs baseline: 1.1007x; 1.1007x over previous
//
#include <hip/hip_runtime.h>

#define NROW 8192
#define DIN  512
#define DOUT 256
#define NCHUNK 256
#define CLEN 32   // NCHUNK*CLEN == NROW

// ---------------- workspace layout (bytes) ----------------
constexpr size_t OFF_H      = 0;                              // 8192*256*4
constexpr size_t OFF_S1     = OFF_H + (size_t)NROW*DOUT*4;    // ---- memset region start
constexpr size_t OFF_S2     = OFF_S1 + NROW*4;
constexpr size_t OFF_RANK   = OFF_S2 + NROW*4;
constexpr size_t OFF_MISC   = OFF_RANK + NROW*4;              // [0]=enc-max u32, [1]=M1 float
constexpr size_t MEMSET_LEN = OFF_MISC + 256 - OFF_S1;        // s1,s2,rank,misc contiguous
constexpr size_t OFF_S1S    = OFF_MISC + 256;
constexpr size_t OFF_PERM   = OFF_S1S + NROW*4;
constexpr size_t OFF_WHI    = OFF_PERM + NROW*4;
constexpr size_t OFF_WLO    = OFF_WHI + NROW*4;
constexpr size_t OFF_PRELOS = OFF_WLO + NROW*4;               // 8193 floats, padded
constexpr size_t OFF_SUFHIS = OFF_PRELOS + 33024;
constexpr size_t OFF_CSLO   = OFF_SUFHIS + 33024;             // [NCHUNK] scalar chunk sums
constexpr size_t OFF_CSHI   = OFF_CSLO + 1024;
constexpr size_t OFF_TLO    = OFF_CSHI + 1024;                // [NCHUNK][256]
constexpr size_t OFF_THI    = OFF_TLO + (size_t)NCHUNK*DOUT*4;
constexpr size_t OFF_PRELO  = OFF_THI + (size_t)NCHUNK*DOUT*4;  // [8193][256]
constexpr size_t OFF_SUFHI  = OFF_PRELO + (size_t)(NROW+1)*DOUT*4;
// bf16 split copies of x and W (hi + lo parts)
constexpr size_t OFF_XHI    = OFF_SUFHI + (size_t)(NROW+1)*DOUT*4;
constexpr size_t OFF_XLO    = OFF_XHI + (size_t)NROW*DIN*2;
constexpr size_t OFF_BHI    = OFF_XLO + (size_t)NROW*DIN*2;
constexpr size_t OFF_BLO    = OFF_BHI + (size_t)DOUT*DIN*2;
constexpr size_t WS_NEED    = OFF_BLO + (size_t)DOUT*DIN*2;

typedef float f32x4 __attribute__((ext_vector_type(4)));
typedef short s16x8 __attribute__((ext_vector_type(8)));

__device__ __forceinline__ unsigned short bf16_rne(float f) {
  unsigned int u = __float_as_uint(f);
  return (unsigned short)((u + 0x7fffu + ((u >> 16) & 1u)) >> 16);
}

// ------- kernel 0: split x,W into bf16 hi/lo pairs (memory-bound, ~5us) ----
// x: 2048 blocks * 256 thr * 8 elems; W: 64 blocks.
__global__ __launch_bounds__(256) void split_inputs(const float* __restrict__ x,
                                                    const float* __restrict__ W,
                                                    unsigned short* __restrict__ Xhi,
                                                    unsigned short* __restrict__ Xlo,
                                                    unsigned short* __restrict__ Bhi,
                                                    unsigned short* __restrict__ Blo) {
  const int b = blockIdx.x;
  const float* src;
  unsigned short *dh, *dl;
  size_t off;
  if (b < 2048) {
    off = ((size_t)b * 256 + threadIdx.x) * 8;
    src = x; dh = Xhi; dl = Xlo;
  } else {
    off = ((size_t)(b - 2048) * 256 + threadIdx.x) * 8;
    src = W; dh = Bhi; dl = Blo;
  }
  float4 u = *(const float4*)(src + off);
  float4 v = *(const float4*)(src + off + 4);
  float f[8] = {u.x, u.y, u.z, u.w, v.x, v.y, v.z, v.w};
  s16x8 hv, lv;
#pragma unroll
  for (int j = 0; j < 8; ++j) {
    unsigned short hh = bf16_rne(f[j]);
    float r = f[j] - __uint_as_float(((unsigned int)hh) << 16);
    hv[j] = (short)hh;
    lv[j] = (short)bf16_rne(r);
  }
  *(s16x8*)(dh + off) = hv;
  *(s16x8*)(dl + off) = lv;
}

// ------- kernel 1: h = x @ W^T via split-bf16 MFMA, fused s1/s2 ------------
// h ~= xh*wh + xl*wh + xh*wl (lo*lo ~2^-18, dropped). Single staging per
// K-step, 12 MFMAs (3 per fragment pair). Tile 64x64, 4 waves 2x2, each wave
// 32x32 = 2x2 frags of v_mfma_f32_16x16x32_bf16. LDS pitch 40 bf16 (80 B =
// 20 dwords): 8-lane groups stride 20 dwords -> all 32 banks covered,
// conflict-free b128. s1/s2 from acc frags: 16-lane shfl reduce + atomicAdd.
__global__ __launch_bounds__(256) void gemm_h_mfma(const unsigned short* __restrict__ Xhi,
                                                   const unsigned short* __restrict__ Xlo,
                                                   const unsigned short* __restrict__ Bhi,
                                                   const unsigned short* __restrict__ Blo,
                                                   const float* __restrict__ a1,
                                                   const float* __restrict__ a2,
                                                   float* __restrict__ h,
                                                   float* __restrict__ s1,
                                                   float* __restrict__ s2) {
  __shared__ unsigned short AsH[64][40], AsL[64][40], BsH[64][40], BsL[64][40];
  const int tid = threadIdx.x;
  const int rowBase = blockIdx.x * 64;
  const int colBase = blockIdx.y * 64;
  const int wid = tid >> 6, lane = tid & 63;
  const int wRow = wid >> 1, wCol = wid & 1;      // 2x2 wave grid
  const int lhi = lane >> 4, llo = lane & 15;

  f32x4 acc[2][2];
#pragma unroll
  for (int m = 0; m < 2; ++m)
#pragma unroll
    for (int n = 0; n < 2; ++n) acc[m][n] = (f32x4)(0.f);

  const int sr = tid >> 2;   // staging row 0..63
  const int sq = tid & 3;    // k-quarter (8 bf16 each)
  const unsigned short* xh = Xhi + (size_t)(rowBase + sr) * DIN + sq * 8;
  const unsigned short* xl = Xlo + (size_t)(rowBase + sr) * DIN + sq * 8;
  const unsigned short* bh = Bhi + (size_t)(colBase + sr) * DIN + sq * 8;
  const unsigned short* bl = Blo + (size_t)(colBase + sr) * DIN + sq * 8;

  s16x8 rah = *(const s16x8*)(xh);
  s16x8 ral = *(const s16x8*)(xl);
  s16x8 rbh = *(const s16x8*)(bh);
  s16x8 rbl = *(const s16x8*)(bl);

  for (int k0 = 0; k0 < DIN; k0 += 32) {
    __syncthreads();  // previous step's frag reads complete
    *(s16x8*)&AsH[sr][sq * 8] = rah;
    *(s16x8*)&AsL[sr][sq * 8] = ral;
    *(s16x8*)&BsH[sr][sq * 8] = rbh;
    *(s16x8*)&BsL[sr][sq * 8] = rbl;
    __syncthreads();  // staged tile visible
    if (k0 + 32 < DIN) {  // prefetch next K-step (latency hides under MFMAs)
      rah = *(const s16x8*)(xh + k0 + 32);
      ral = *(const s16x8*)(xl + k0 + 32);
      rbh = *(const s16x8*)(bh + k0 + 32);
      rbl = *(const s16x8*)(bl + k0 + 32);
    }
    s16x8 afh[2], afl[2], bfh[2], bfl[2];
#pragma unroll
    for (int m = 0; m < 2; ++m) {
      afh[m] = *(const s16x8*)&AsH[wRow * 32 + m * 16 + llo][lhi * 8];
      afl[m] = *(const s16x8*)&AsL[wRow * 32 + m * 16 + llo][lhi * 8];
    }
#pragma unroll
    for (int n = 0; n < 2; ++n) {
      bfh[n] = *(const s16x8*)&BsH[wCol * 32 + n * 16 + llo][lhi * 8];
      bfl[n] = *(const s16x8*)&BsL[wCol * 32 + n * 16 + llo][lhi * 8];
    }
#pragma unroll
    for (int m = 0; m < 2; ++m)
#pragma unroll
      for (int n = 0; n < 2; ++n) {
        acc[m][n] = __builtin_amdgcn_mfma_f32_16x16x32_bf16(afh[m], bfh[n], acc[m][n], 0, 0, 0);
        acc[m][n] = __builtin_amdgcn_mfma_f32_16x16x32_bf16(afl[m], bfh[n], acc[m][n], 0, 0, 0);
        acc[m][n] = __builtin_amdgcn_mfma_f32_16x16x32_bf16(afh[m], bfl[n], acc[m][n], 0, 0, 0);
      }
  }
  // C/D layout (m89-verified): col = lane&15, row = (lane>>4)*4 + reg
  float a1c[2], a2c[2];
#pragma unroll
  for (int n = 0; n < 2; ++n) {
    const int col = colBase + wCol * 32 + n * 16 + llo;
    a1c[n] = a1[col];
    a2c[n] = a2[col];
  }
#pragma unroll
  for (int m = 0; m < 2; ++m) {
    float p1[4] = {0.f, 0.f, 0.f, 0.f}, p2[4] = {0.f, 0.f, 0.f, 0.f};
#pragma unroll
    for (int n = 0; n < 2; ++n) {
      const int col = colBase + wCol * 32 + n * 16 + llo;
#pragma unroll
      for (int j = 0; j < 4; ++j) {
        const int row = rowBase + wRow * 32 + m * 16 + lhi * 4 + j;
        h[(size_t)row * DOUT + col] = acc[m][n][j];
        p1[j] = fmaf(acc[m][n][j], a1c[n], p1[j]);
        p2[j] = fmaf(acc[m][n][j], a2c[n], p2[j]);
      }
    }
#pragma unroll
    for (int j = 0; j < 4; ++j) {
#pragma unroll
      for (int msk = 1; msk < 16; msk <<= 1) {
        p1[j] += __shfl_xor(p1[j], msk);
        p2[j] += __shfl_xor(p2[j], msk);
      }
    }
    if (llo == 0) {
#pragma unroll
      for (int j = 0; j < 4; ++j) {
        const int row = rowBase + wRow * 32 + m * 16 + lhi * 4 + j;
        atomicAdd(&s1[row], p1[j]);
        atomicAdd(&s2[row], p2[j]);
      }
    }
  }
}

// ------- kernel 2: rank by counting (atomicAdd into rank) + global max -----
__global__ __launch_bounds__(256) void rank_count(const float* __restrict__ s1,
                                                  int* __restrict__ rank,
                                                  unsigned int* __restrict__ miscu) {
  __shared__ float sj[1024];
  __shared__ float wm[4];
  const int t = threadIdx.x;
  const int ib = blockIdx.x, jc = blockIdx.y;
  const int j0 = jc * 1024;
  *(float4*)&sj[t << 2] = *(const float4*)(s1 + j0 + (t << 2));
  const int i = ib * 256 + t;
  const float v = s1[i];
  __syncthreads();
  int cnt = 0;
#pragma unroll 4
  for (int q = 0; q < 256; ++q) {
    float4 sv = *(const float4*)&sj[q << 2];
    int jg = j0 + (q << 2);
    cnt += (int)(sv.x < v) + (int)((sv.x == v) & (jg + 0 < i));
    cnt += (int)(sv.y < v) + (int)((sv.y == v) & (jg + 1 < i));
    cnt += (int)(sv.z < v) + (int)((sv.z == v) & (jg + 2 < i));
    cnt += (int)(sv.w < v) + (int)((sv.w == v) & (jg + 3 < i));
  }
  atomicAdd(&rank[i], cnt);
  if (jc == 0) {  // one layer computes global max of s1 (monotone-uint atomicMax)
    float m = v;
#pragma unroll
    for (int off = 32; off > 0; off >>= 1) m = fmaxf(m, __shfl_down(m, off));
    if ((t & 63) == 0) wm[t >> 6] = m;
    __syncthreads();
    if (t == 0) {
      float mm = fmaxf(fmaxf(wm[0], wm[1]), fmaxf(wm[2], wm[3]));
      unsigned int b = __float_as_uint(mm);
      unsigned int enc = (b & 0x80000000u) ? ~b : (b | 0x80000000u);
      atomicMax(miscu, enc);
    }
  }
}

// ------- kernel 3: scatter into sorted order + exp weights -----------------
__global__ __launch_bounds__(256) void scatter_w(const float* __restrict__ s1,
                                                 const int* __restrict__ rank,
                                                 const unsigned int* __restrict__ miscu,
                                                 float* __restrict__ miscf,
                                                 float* __restrict__ s1s,
                                                 int* __restrict__ perm,
                                                 float* __restrict__ w_hi,
                                                 float* __restrict__ w_lo) {
  const int i = blockIdx.x * 256 + threadIdx.x;
  unsigned int e = miscu[0];
  unsigned int b = (e & 0x80000000u) ? (e & 0x7fffffffu) : ~e;
  const float M1 = __uint_as_float(b);
  const float v = s1[i];
  const int r = rank[i];
  s1s[r] = v;
  perm[r] = i;
  w_hi[r] = __expf(v - M1);
  w_lo[r] = __expf(0.2f * (v - M1));
  if (i == 0) miscf[0] = M1;
}

// ------- kernel 4: per-chunk weighted totals + scalar chunk sums -----------
__global__ __launch_bounds__(256) void chunk_totals(const float* __restrict__ h,
                                                    const int* __restrict__ perm,
                                                    const float* __restrict__ w_hi,
                                                    const float* __restrict__ w_lo,
                                                    float* __restrict__ T_lo,
                                                    float* __restrict__ T_hi,
                                                    float* __restrict__ cs_lo,
                                                    float* __restrict__ cs_hi) {
  const int d = threadIdx.x, b = blockIdx.x;
  const int j0 = b * CLEN;
  float tlo = 0.f, thi = 0.f;
#pragma unroll
  for (int e = 0; e < CLEN; e += 4) {
    int4 p4 = *(const int4*)(perm + j0 + e);
    float4 wl4 = *(const float4*)(w_lo + j0 + e);
    float4 wh4 = *(const float4*)(w_hi + j0 + e);
    float h0 = h[(size_t)p4.x * DOUT + d];
    float h1 = h[(size_t)p4.y * DOUT + d];
    float h2 = h[(size_t)p4.z * DOUT + d];
    float h3 = h[(size_t)p4.w * DOUT + d];
    tlo += wl4.x * h0 + wl4.y * h1 + wl4.z * h2 + wl4.w * h3;
    thi += wh4.x * h0 + wh4.y * h1 + wh4.z * h2 + wh4.w * h3;
  }
  T_lo[b * DOUT + d] = tlo;
  T_hi[b * DOUT + d] = thi;
  if (d < 64) {  // wave 0: scalar sums of this chunk's weights
    float wl = (d < 32) ? w_lo[j0 + d] : 0.f;
    float wh = (d < 32) ? w_hi[j0 + d] : 0.f;
#pragma unroll
    for (int off = 32; off > 0; off >>= 1) {
      wl += __shfl_down(wl, off);
      wh += __shfl_down(wh, off);
    }
    if (d == 0) { cs_lo[b] = wl; cs_hi[b] = wh; }
  }
}

// ------- kernel 5: chunk-offset sums + materialize PreLo/SufHi + scalars ---
__global__ __launch_bounds__(256) void write_prefix(const float* __restrict__ h,
                                                    const int* __restrict__ perm,
                                                    const float* __restrict__ w_hi,
                                                    const float* __restrict__ w_lo,
                                                    const float* __restrict__ T_lo,
                                                    const float* __restrict__ T_hi,
                                                    const float* __restrict__ cs_lo,
                                                    const float* __restrict__ cs_hi,
                                                    float* __restrict__ PreLo,
                                                    float* __restrict__ SufHi,
                                                    float* __restrict__ prelo_s,
                                                    float* __restrict__ sufhi_s) {
  const int d = threadIdx.x, b = blockIdx.x;
  const int j0 = b * CLEN;
  // wave 0 additionally computes the scalar denominator prefixes
  if (d < 64) {
    float accp = 0.f, acct = 0.f;
    for (int p = d; p < NCHUNK; p += 64) {
      float cl = cs_lo[p], ch = cs_hi[p];
      accp += (p < b) ? cl : 0.f;
      acct += (p > b) ? ch : 0.f;
    }
#pragma unroll
    for (int off = 32; off > 0; off >>= 1) {
      accp += __shfl_down(accp, off);
      acct += __shfl_down(acct, off);
    }
    float pres  = __shfl(accp, 0);
    float tails = __shfl(acct, 0);
    float wl = (d < 32) ? w_lo[j0 + d] : 0.f;
    float wh = (d < 32) ? w_hi[j0 + d] : 0.f;
    float pl = wl, ph = wh;  // inclusive prefix over 32 lanes
#pragma unroll
    for (int off = 1; off < 32; off <<= 1) {
      float a = __shfl_up(pl, off);
      float c = __shfl_up(ph, off);
      if (d >= off) { pl += a; ph += c; }
    }
    float chunk_hi_tot = __shfl(ph, 31);
    if (d < 32) {
      prelo_s[j0 + d] = pres + (pl - wl);
      sufhi_s[j0 + d] = tails + (chunk_hi_tot - (ph - wh));
    }
    if (b == NCHUNK - 1 && d == 31) {
      prelo_s[NROW] = pres + pl;
      sufhi_s[NROW] = 0.f;
    }
  }
  float rl = 0.f, tail = 0.f;
#pragma unroll 8
  for (int p = 0; p < NCHUNK; ++p) {
    float vl = T_lo[p * DOUT + d];
    float vh = T_hi[p * DOUT + d];
    rl   += (p < b) ? vl : 0.f;
    tail += (p > b) ? vh : 0.f;
  }
  float hv[CLEN], wlv[CLEN], whv[CLEN];
  float ownHi = 0.f;
#pragma unroll
  for (int e = 0; e < CLEN; e += 4) {
    int4 p4 = *(const int4*)(perm + j0 + e);
    float4 wl4 = *(const float4*)(w_lo + j0 + e);
    float4 wh4 = *(const float4*)(w_hi + j0 + e);
    hv[e + 0] = h[(size_t)p4.x * DOUT + d];
    hv[e + 1] = h[(size_t)p4.y * DOUT + d];
    hv[e + 2] = h[(size_t)p4.z * DOUT + d];
    hv[e + 3] = h[(size_t)p4.w * DOUT + d];
    wlv[e + 0] = wl4.x; wlv[e + 1] = wl4.y; wlv[e + 2] = wl4.z; wlv[e + 3] = wl4.w;
    whv[e + 0] = wh4.x; whv[e + 1] = wh4.y; whv[e + 2] = wh4.z; whv[e + 3] = wh4.w;
    ownHi += wh4.x * hv[e] + wh4.y * hv[e + 1] + wh4.z * hv[e + 2] + wh4.w * hv[e + 3];
  }
  float shb = tail + ownHi;
  float preh = 0.f;
#pragma unroll
  for (int e = 0; e < CLEN; ++e) {
    size_t j = (size_t)(j0 + e);
    PreLo[j * DOUT + d] = rl;
    SufHi[j * DOUT + d] = shb - preh;
    rl   += wlv[e] * hv[e];
    preh += whv[e] * hv[e];
  }
  if (b == NCHUNK - 1) {
    PreLo[(size_t)NROW * DOUT + d] = rl;
    SufHi[(size_t)NROW * DOUT + d] = 0.f;
  }
}

// ---------------- kernel 6: per-row combine -------------------------------
__global__ __launch_bounds__(256) void finalize(const float* __restrict__ s2,
                                                const float* __restrict__ s1s,
                                                const float* __restrict__ miscf,
                                                const float* __restrict__ PreLo,
                                                const float* __restrict__ SufHi,
                                                const float* __restrict__ prelo_s,
                                                const float* __restrict__ sufhi_s,
                                                float* __restrict__ out) {
  const int wave = threadIdx.x >> 6, lane = threadIdx.x & 63;
  const int i = blockIdx.x * 4 + wave;
  const float c = s2[i];
  const float M1 = miscf[0];
  const float tval = -c;
  int lo = 0, hi = NROW;
  while (lo < hi) {
    int mid = (lo + hi) >> 1;
    if (s1s[mid] <= tval) lo = mid + 1; else hi = mid;
  }
  const int k = lo;
  const float u = c + M1;
  const float m = fmaxf(u, 0.2f * u);
  const float fh = __expf(u - m);
  const float fl = __expf(0.2f * u - m);
  const float den = fh * sufhi_s[k] + fl * prelo_s[k];
  const float inv = 1.f / den;
  float4 A = *(const float4*)(SufHi + (size_t)k * DOUT + (lane << 2));
  float4 B = *(const float4*)(PreLo + (size_t)k * DOUT + (lane << 2));
  float4 o;
  o.x = (fh * A.x + fl * B.x) * inv;
  o.y = (fh * A.y + fl * B.y) * inv;
  o.z = (fh * A.z + fl * B.z) * inv;
  o.w = (fh * A.w + fl * B.w) * inv;
  *(float4*)(out + (size_t)i * DOUT + (lane << 2)) = o;
}

extern "C" void kernel_launch(void* const* d_in, const int* in_sizes, int n_in,
                              void* d_out, int out_size, void* d_ws, size_t ws_size,
                              hipStream_t stream) {
  const float* x  = (const float*)d_in[0];
  const float* W  = (const float*)d_in[2];
  const float* a1 = (const float*)d_in[3];
  const float* a2 = (const float*)d_in[4];
  float* out = (float*)d_out;

  char* ws = (char*)d_ws;
  if (ws_size < WS_NEED) ws = (char*)d_in[1];  // fall back to unused adj buffer

  float*          h       = (float*)(ws + OFF_H);
  float*          s1      = (float*)(ws + OFF_S1);
  float*          s2      = (float*)(ws + OFF_S2);
  int*            rank    = (int*)  (ws + OFF_RANK);
  unsigned int*   miscu   = (unsigned int*)(ws + OFF_MISC);
  float*          miscf   = (float*)(ws + OFF_MISC) + 1;
  float*          s1s     = (float*)(ws + OFF_S1S);
  int*            perm    = (int*)  (ws + OFF_PERM);
  float*          w_hi    = (float*)(ws + OFF_WHI);
  float*          w_lo    = (float*)(ws + OFF_WLO);
  float*          prelo_s = (float*)(ws + OFF_PRELOS);
  float*          sufhi_s = (float*)(ws + OFF_SUFHIS);
  float*          cs_lo   = (float*)(ws + OFF_CSLO);
  float*          cs_hi   = (float*)(ws + OFF_CSHI);
  float*          T_lo    = (float*)(ws + OFF_TLO);
  float*          T_hi    = (float*)(ws + OFF_THI);
  float*          PreLo   = (float*)(ws + OFF_PRELO);
  float*          SufHi   = (float*)(ws + OFF_SUFHI);
  unsigned short* Xhi     = (unsigned short*)(ws + OFF_XHI);
  unsigned short* Xlo     = (unsigned short*)(ws + OFF_XLO);
  unsigned short* Bhi     = (unsigned short*)(ws + OFF_BHI);
  unsigned short* Blo     = (unsigned short*)(ws + OFF_BLO);

  // zero s1,s2,rank,misc (contiguous) for the atomic accumulations
  hipMemsetAsync(s1, 0, MEMSET_LEN, stream);

  split_inputs<<<2048 + 64, 256, 0, stream>>>(x, W, Xhi, Xlo, Bhi, Blo);
  gemm_h_mfma<<<dim3(NROW / 64, DOUT / 64), 256, 0, stream>>>(Xhi, Xlo, Bhi, Blo,
                                                              a1, a2, h, s1, s2);
  rank_count<<<dim3(NROW / 256, 8), 256, 0, stream>>>(s1, rank, miscu);
  scatter_w<<<NROW / 256, 256, 0, stream>>>(s1, rank, miscu, miscf, s1s, perm, w_hi, w_lo);
  chunk_totals<<<NCHUNK, 256, 0, stream>>>(h, perm, w_hi, w_lo, T_lo, T_hi, cs_lo, cs_hi);
  write_prefix<<<NCHUNK, 256, 0, stream>>>(h, perm, w_hi, w_lo, T_lo, T_hi, cs_lo, cs_hi,
                                           PreLo, SufHi, prelo_s, sufhi_s);
  finalize<<<NROW / 4, 256, 0, stream>>>(s2, s1s, miscf, PreLo, SufHi, prelo_s, sufhi_s, out);
}